// Round 4
// baseline (30.731 us; speedup 1.0000x reference)
//
#include <hip/hip_runtime.h>

#define NC 4  // N_COORD

__global__ __launch_bounds__(256) void wvfn_kernel(
    const float* __restrict__ Rs,   // [W, 4, 3] f32
    const float* __restrict__ A,    // [4] f32
    const float* __restrict__ C,    // [4] f32 (complex64 normalized to real f32 by harness)
    float* __restrict__ out,        // [W f32 (Re out0)] ++ [W f32 (out1)]
    int W)
{
    int w = blockIdx.x * blockDim.x + threadIdx.x;
    if (w >= W) return;

    // ---- load 12 coords as 3x float4 (48B per walker, 16B aligned) ----
    const float4* p = (const float4*)(Rs + (size_t)w * 12);
    float4 q0 = p[0];
    float4 q1 = p[1];
    float4 q2 = p[2];

    float x0 = q0.x, y0 = q0.y, z0 = q0.z;
    float x1 = q0.w, y1 = q1.x, z1 = q1.y;
    float x2 = q1.z, y2 = q1.w, z2 = q2.x;
    float x3 = q2.y, y3 = q2.z, z3 = q2.w;

    // ---- radii, r_sum, invr_sum ----
    float d0 = x0*x0 + y0*y0 + z0*z0;
    float d1 = x1*x1 + y1*y1 + z1*z1;
    float d2 = x2*x2 + y2*y2 + z2*z2;
    float d3 = x3*x3 + y3*y3 + z3*z3;

    float r0 = sqrtf(d0), r1 = sqrtf(d1), r2 = sqrtf(d2), r3 = sqrtf(d3);
    float r_sum    = r0 + r1 + r2 + r3;
    float invr_sum = 1.0f/r0 + 1.0f/r1 + 1.0f/r2 + 1.0f/r3;

    // ---- all-pairs Coulomb: V = -sum_{a<b} 1/|r_a - r_b|  (VB = 1) ----
    float V = 0.0f;
    {
        float dx, dy, dz, dd;
        dx = x0-x1; dy = y0-y1; dz = z0-z1; dd = dx*dx+dy*dy+dz*dz; V += 1.0f/sqrtf(dd);
        dx = x0-x2; dy = y0-y2; dz = z0-z2; dd = dx*dx+dy*dy+dz*dz; V += 1.0f/sqrtf(dd);
        dx = x0-x3; dy = y0-y3; dz = z0-z3; dd = dx*dx+dy*dy+dz*dz; V += 1.0f/sqrtf(dd);
        dx = x1-x2; dy = y1-y2; dz = z1-z2; dd = dx*dx+dy*dy+dz*dz; V += 1.0f/sqrtf(dd);
        dx = x1-x3; dy = y1-y3; dz = z1-z3; dd = dx*dx+dy*dy+dz*dz; V += 1.0f/sqrtf(dd);
        dx = x2-x3; dy = y2-y3; dz = z2-z3; dd = dx*dx+dy*dy+dz*dz; V += 1.0f/sqrtf(dd);
        V = -V;
    }

    // ---- psi, nabla_psi over the N=4 ansatz terms (C real) ----
    float psi = 0.0f;
    float nab = 0.0f;
    #pragma unroll
    for (int n = 0; n < NC; ++n) {
        float a    = A[n];
        float invA = 1.0f / a;
        float e    = expf(-r_sum * invA);
        float lap  = (float)NC * invA * invA - 2.0f * invA * invr_sum;
        float cre  = C[n];          // real-only; imag dropped by harness
        psi += cre * e;
        nab += cre * e * lap;
    }

    // ---- H = -0.5*nabla + V*psi ; out0 = psi*H (real) ; out1 = psi^2 ----
    float H = -0.5f * nab + V * psi;

    out[w]             = psi * H;
    out[(size_t)W + w] = psi * psi;
}

extern "C" void kernel_launch(void* const* d_in, const int* in_sizes, int n_in,
                              void* d_out, int out_size, void* d_ws, size_t ws_size,
                              hipStream_t stream) {
    const float* Rs = (const float*)d_in[0];
    const float* A  = (const float*)d_in[1];
    const float* C  = (const float*)d_in[2];   // complex64 -> real f32 [4]
    float* out = (float*)d_out;

    int W = in_sizes[0] / 12;                  // [W, 4, 3]
    int block = 256;
    int grid  = (W + block - 1) / block;
    wvfn_kernel<<<grid, block, 0, stream>>>(Rs, A, C, out, W);
}

// Round 5
// 24.781 us; speedup vs baseline: 1.2401x; 1.2401x over previous
//
#include <hip/hip_runtime.h>

#define NC 4  // N_COORD

__global__ __launch_bounds__(256) void wvfn_kernel(
    const float* __restrict__ Rs,   // [W, 4, 3] f32
    const float* __restrict__ A,    // [4] f32
    const float* __restrict__ C,    // [4] f32 (complex64 -> real f32 by harness)
    float* __restrict__ out,        // [W f32 (Re out0)] ++ [W f32 (out1)]
    int W)
{
    __shared__ float4 sh[768];      // 256 walkers * 3 float4 = 12 KB

    const int t = threadIdx.x;
    const size_t blk_first_q = (size_t)blockIdx.x * 768;      // first float4 of this block
    const size_t total_q     = (size_t)W * 3;                 // total float4s in Rs

    // ---- coalesced global -> LDS: 3 contiguous 1024B wave transactions ----
    const float4* g = (const float4*)Rs;
    #pragma unroll
    for (int k = 0; k < 3; ++k) {
        size_t q = blk_first_q + t + k * 256;
        if (q < total_q) sh[t + k * 256] = g[q];
    }
    __syncthreads();

    const int w = blockIdx.x * 256 + t;
    if (w >= W) return;

    // ---- per-walker read from LDS (byte addr 48t: banks spread evenly, conflict-free) ----
    float4 q0 = sh[3 * t + 0];
    float4 q1 = sh[3 * t + 1];
    float4 q2 = sh[3 * t + 2];

    float x0 = q0.x, y0 = q0.y, z0 = q0.z;
    float x1 = q0.w, y1 = q1.x, z1 = q1.y;
    float x2 = q1.z, y2 = q1.w, z2 = q2.x;
    float x3 = q2.y, y3 = q2.z, z3 = q2.w;

    // ---- radii, r_sum, invr_sum via rsqrt ----
    float d0 = x0*x0 + y0*y0 + z0*z0;
    float d1 = x1*x1 + y1*y1 + z1*z1;
    float d2 = x2*x2 + y2*y2 + z2*z2;
    float d3 = x3*x3 + y3*y3 + z3*z3;

    float i0 = rsqrtf(d0), i1 = rsqrtf(d1), i2 = rsqrtf(d2), i3 = rsqrtf(d3);
    float r0 = d0 * i0, r1 = d1 * i1, r2 = d2 * i2, r3 = d3 * i3;
    float r_sum    = r0 + r1 + r2 + r3;
    float invr_sum = i0 + i1 + i2 + i3;

    // ---- all-pairs Coulomb: V = -sum_{a<b} rsqrt(|ra-rb|^2)  (VB = 1) ----
    float V = 0.0f;
    {
        float dx, dy, dz, dd;
        dx = x0-x1; dy = y0-y1; dz = z0-z1; dd = dx*dx+dy*dy+dz*dz; V += rsqrtf(dd);
        dx = x0-x2; dy = y0-y2; dz = z0-z2; dd = dx*dx+dy*dy+dz*dz; V += rsqrtf(dd);
        dx = x0-x3; dy = y0-y3; dz = z0-z3; dd = dx*dx+dy*dy+dz*dz; V += rsqrtf(dd);
        dx = x1-x2; dy = y1-y2; dz = z1-z2; dd = dx*dx+dy*dy+dz*dz; V += rsqrtf(dd);
        dx = x1-x3; dy = y1-y3; dz = z1-z3; dd = dx*dx+dy*dy+dz*dz; V += rsqrtf(dd);
        dx = x2-x3; dy = y2-y3; dz = z2-z3; dd = dx*dx+dy*dy+dz*dz; V += rsqrtf(dd);
        V = -V;
    }

    // ---- psi, nabla_psi over the N=4 ansatz terms (C real) ----
    float psi = 0.0f;
    float nab = 0.0f;
    #pragma unroll
    for (int n = 0; n < NC; ++n) {
        float a    = A[n];
        float invA = 1.0f / a;
        float e    = expf(-r_sum * invA);
        float lap  = (float)NC * invA * invA - 2.0f * invA * invr_sum;
        float cre  = C[n];
        psi += cre * e;
        nab += cre * e * lap;
    }

    // ---- H = -0.5*nabla + V*psi ; out0 = psi*H ; out1 = psi^2 ----
    float H = -0.5f * nab + V * psi;

    out[w]             = psi * H;
    out[(size_t)W + w] = psi * psi;
}

extern "C" void kernel_launch(void* const* d_in, const int* in_sizes, int n_in,
                              void* d_out, int out_size, void* d_ws, size_t ws_size,
                              hipStream_t stream) {
    const float* Rs = (const float*)d_in[0];
    const float* A  = (const float*)d_in[1];
    const float* C  = (const float*)d_in[2];
    float* out = (float*)d_out;

    int W = in_sizes[0] / 12;                  // [W, 4, 3]
    int block = 256;
    int grid  = (W + block - 1) / block;
    wvfn_kernel<<<grid, block, 0, stream>>>(Rs, A, C, out, W);
}